// Round 6
// baseline (622.171 us; speedup 1.0000x reference)
//
#include <hip/hip_runtime.h>
#include <math.h>

#define IH 2048
#define IW 2048
#define NBATCH 8
#define TW 64            // tile width  (output)
#define TH 16            // tile height (output) -> one 16-row block band
#define HALO 3
#define SR (TH + 2*HALO) // 22 staged rows
#define SROW 72          // s_img row stride (floats); L = gcol-ox+4, L=0..71
#define MROW 128         // s_m row stride: 32 float4 of (mu,mu2) pairs
#define ACT_TH 0.1f
#define IMP_TH 0.1f

// 1D Gaussian taps, sigma = 7/6, normalized.
#define G0 0.0125602013f
#define G1 0.0788279697f
#define G2 0.2372960895f
#define G3 0.3426314790f

// ---- DPP wave reductions (VALU pipe, zero LDS traffic) -------------------
// sum: bound_ctrl=1 -> invalid source lanes read 0 (harmless for add)
#define DPPA(v, CTRL) \
    ((v) + __int_as_float(__builtin_amdgcn_update_dpp( \
        0, __float_as_int(v), (CTRL), 0xf, 0xf, true)))
// min: old = v, bound_ctrl=0 -> invalid lanes keep v (harmless for min)
#define DPPM(v, CTRL) \
    fminf((v), __int_as_float(__builtin_amdgcn_update_dpp( \
        __float_as_int(v), __float_as_int(v), (CTRL), 0xf, 0xf, false)))

__device__ inline float wave_sum64(float v) {
    v = DPPA(v, 0xB1);   // quad_perm xor1
    v = DPPA(v, 0x4E);   // quad_perm xor2
    v = DPPA(v, 0x141);  // row_half_mirror (xor within 8)
    v = DPPA(v, 0x140);  // row_mirror (xor within 16)
    v = DPPA(v, 0x142);  // row_bcast15
    v = DPPA(v, 0x143);  // row_bcast31 -> lanes 48..63 hold the total
    return v;
}
__device__ inline float wave_min64(float v) {
    v = DPPM(v, 0xB1);
    v = DPPM(v, 0x4E);
    v = DPPM(v, 0x141);
    v = DPPM(v, 0x140);
    v = DPPM(v, 0x142);
    v = DPPM(v, 0x143);
    return v;
}

// ---------------- Kernel 1: per-batch max --------------------------------
__global__ __launch_bounds__(256) void batch_max_kernel(
    const float* __restrict__ x, unsigned int* __restrict__ maxbits)
{
    const int b = blockIdx.y;
    const float4* p = (const float4*)(x + (size_t)b * (size_t)(IH * IW));
    const int t = blockIdx.x * 256 + threadIdx.x;    // 0..65535
    float m0 = 0.0f, m1 = 0.0f, m2 = 0.0f, m3 = 0.0f;
    for (int j = 0; j < 16; j += 4) {
        float4 a = p[t + (size_t)(j + 0) * 65536];
        float4 c = p[t + (size_t)(j + 1) * 65536];
        float4 d = p[t + (size_t)(j + 2) * 65536];
        float4 e = p[t + (size_t)(j + 3) * 65536];
        m0 = fmaxf(m0, fmaxf(fmaxf(a.x, a.y), fmaxf(a.z, a.w)));
        m1 = fmaxf(m1, fmaxf(fmaxf(c.x, c.y), fmaxf(c.z, c.w)));
        m2 = fmaxf(m2, fmaxf(fmaxf(d.x, d.y), fmaxf(d.z, d.w)));
        m3 = fmaxf(m3, fmaxf(fmaxf(e.x, e.y), fmaxf(e.z, e.w)));
    }
    float m = fmaxf(fmaxf(m0, m1), fmaxf(m2, m3));
#pragma unroll
    for (int s = 1; s < 64; s <<= 1) m = fmaxf(m, __shfl_xor(m, s));
    __shared__ float sm[4];
    const int lane = threadIdx.x & 63, wv = threadIdx.x >> 6;
    if (lane == 0) sm[wv] = m;
    __syncthreads();
    if (threadIdx.x == 0) {
        m = fmaxf(fmaxf(sm[0], sm[1]), fmaxf(sm[2], sm[3]));
        atomicMax(&maxbits[b], __float_as_uint(m));   // x>=0: bit cmp == fp cmp
    }
}

// ---------------- Kernel 2: fused normalize + block stats ----------------
// 64x16 tile; LDS 17.6KB -> 8 WG/CU = 32 waves (100% occupancy ceiling).
// One wave == one 16x16 stats block (4 blocks/tile, 4 waves/WG).
__global__ __launch_bounds__(256, 8) void piqe_main_kernel(
    const float* __restrict__ x, const unsigned int* __restrict__ maxbits,
    float* __restrict__ contrib_sum, unsigned int* __restrict__ nhsa)
{
    __shared__ float s_img[SR * SROW];   // 22x72 img; later MSCN n in-place
    __shared__ float s_m[SR * MROW];     // 22 rows x 32 float4 (mu,mu2 pairs)
    __shared__ float s_c;
    __shared__ unsigned int s_a;

    const int tid = threadIdx.x;
    const int b = blockIdx.z;
    const int ox = blockIdx.x * TW;
    const int oy = blockIdx.y * TH;
    const float* img0 = x + (size_t)b * (size_t)(IH * IW);
    const float scale = 255.0f / __uint_as_float(maxbits[b]);

    if (tid == 0) { s_c = 0.0f; s_a = 0u; }

    // ---- Phase A: stage 22x72 (edge-clamped), img = rint(x*scale).
    // Interior x-tiles: 18 coalesced float4 per row cover L=0..71.
    if (ox > 0 && ox < IW - TW) {
        for (int i = tid; i < SR * 18; i += 256) {
            int r = i / 18, c = i - r * 18;
            int gy = oy + r - HALO; gy = max(0, min(IH - 1, gy));
            float4 vv = *(const float4*)(img0 + (size_t)gy * IW + (ox - 4) + 4 * c);
            float4 w4;
            w4.x = rintf(vv.x * scale);
            w4.y = rintf(vv.y * scale);
            w4.z = rintf(vv.z * scale);
            w4.w = rintf(vv.w * scale);
            *(float4*)&s_img[r * SROW + 4 * c] = w4;   // full bank sweep
        }
    } else {                                           // ox==0 / ox==1984
        for (int i = tid; i < SR * SROW; i += 256) {
            int r = i / SROW, L = i - r * SROW;
            int gy = oy + r - HALO; gy = max(0, min(IH - 1, gy));
            int gx = ox + L - 4; gx = max(0, min(IW - 1, gx));
            s_img[i] = rintf(img0[(size_t)gy * IW + gx] * scale);
        }
    }
    __syncthreads();

    const float gk[7] = {G0, G1, G2, G3, G2, G1, G0};

    // ---- Phase B: horizontal 7-tap (img, img^2) -> s_m interleaved.
    // 16 threads/row, 4 outputs each; 3 aligned b128 reads (full bank sweep).
    {
        const int c4 = (tid & 15) << 2;
        for (int r = tid >> 4; r < SR; r += 16) {
            const float* p = &s_img[r * SROW + c4];
            float v[12];
            *(float4*)(v)     = *(const float4*)(p);
            *(float4*)(v + 4) = *(const float4*)(p + 4);
            *(float4*)(v + 8) = *(const float4*)(p + 8);
            float q[11];
#pragma unroll
            for (int i = 1; i < 11; ++i) q[i] = v[i] * v[i];
            float om[4], om2[4];
#pragma unroll
            for (int j = 0; j < 4; ++j) {
                float m = 0.0f, m2 = 0.0f;
#pragma unroll
                for (int k = 0; k < 7; ++k) {
                    m  = fmaf(gk[k], v[1 + j + k], m);
                    m2 = fmaf(gk[k], q[1 + j + k], m2);
                }
                om[j] = m; om2[j] = m2;
            }
            float4 pa, pb;
            pa.x = om[0]; pa.y = om2[0]; pa.z = om[1]; pa.w = om2[1];
            pb.x = om[2]; pb.y = om2[2]; pb.z = om[3]; pb.w = om2[3];
            *(float4*)&s_m[r * MROW + 2 * c4]     = pa;
            *(float4*)&s_m[r * MROW + 2 * c4 + 4] = pb;
        }
    }
    __syncthreads();

    // ---- Phase C: vertical 7-tap, n = (img-mu)/(std+1) in-place in s_img.
    // thread = (col pair cp, 2-row group rg); 8 b128 reads (full bank sweep),
    // float2 writes (full sweep). Each thread touches only its own pixels.
    {
        const int cp = tid & 31;
        const int r0 = (tid >> 5) * 2;
        float4 f[8];
#pragma unroll
        for (int i = 0; i < 8; ++i)
            f[i] = *(const float4*)&s_m[(r0 + i) * MROW + 4 * cp];
#pragma unroll
        for (int i = 0; i < 2; ++i) {
            float mA = 0.0f, m2A = 0.0f, mB = 0.0f, m2B = 0.0f;
#pragma unroll
            for (int k = 0; k < 7; ++k) {
                mA  = fmaf(gk[k], f[i + k].x, mA);
                m2A = fmaf(gk[k], f[i + k].y, m2A);
                mB  = fmaf(gk[k], f[i + k].z, mB);
                m2B = fmaf(gk[k], f[i + k].w, m2B);
            }
            float sdA = __builtin_amdgcn_sqrtf(fabsf(m2A - mA * mA));
            float sdB = __builtin_amdgcn_sqrtf(fabsf(m2B - mB * mB));
            int ii = (r0 + i + HALO) * SROW + 2 * cp + 4;
            float2 pix = *(float2*)&s_img[ii];
            float2 nn;
            nn.x = (pix.x - mA) * __builtin_amdgcn_rcpf(sdA + 1.0f);
            nn.y = (pix.y - mB) * __builtin_amdgcn_rcpf(sdB + 1.0f);
            *(float2*)&s_img[ii] = nn;
        }
    }
    __syncthreads();

    // ---- Phase D: one wave per 16x16 block. lane = (row = t>>2, quarter
    // q = t&3): one b128 per lane (worst 2-way aliasing = free). All
    // reductions via DPP on the VALU pipe; result lands in lanes 48..63.
    {
        const int wv = tid >> 6;               // block bj = wave id
        const int t = tid & 63;
        const int row = t >> 2, q = t & 3;
        const float* np0 = &s_img[HALO * SROW + wv * 16 + 4];
        float4 v = *(const float4*)(np0 + row * SROW + 4 * q);

        float s1 = v.x + v.y + v.z + v.w;
        float s2 = v.x * v.x + v.y * v.y + v.z * v.z + v.w * v.w;
        // center cols {7,8}: q1 owns col7 (v.w), q2 owns col8 (v.x)
        float cv = (q == 1) ? v.w : ((q == 2) ? v.x : 0.0f);
        float c1 = cv, c2 = cv * cv;
        // sur excludes cols {7,9}: q1 drops col7 (v.w), q2 drops col9 (v.y)
        float ev = (q == 1) ? v.w : ((q == 2) ? v.y : 0.0f);
        float u1 = s1 - ev, u2 = s2 - ev * ev;

        // Edge 6-window stds: 4 edges x 11 windows = 44 evals, one per lane.
        float minstd = __builtin_inff();
        if (t < 44) {
            int edge = t / 11;                 // const-div -> magic mul
            int w = t - edge * 11;
            const float* qp;
            int step;
            if (edge == 0)      { qp = np0 + w;             step = 1;    }
            else if (edge == 1) { qp = np0 + 15 * SROW + w; step = 1;    }
            else if (edge == 2) { qp = np0 + w * SROW;      step = SROW; }
            else                { qp = np0 + w * SROW + 15; step = SROW; }
            float a1 = 0.0f, a2 = 0.0f;
#pragma unroll
            for (int j = 0; j < 6; ++j) {
                float vv = qp[j * step];
                a1 += vv;
                a2 = fmaf(vv, vv, a2);
            }
            float var = (a2 - a1 * a1 * (1.0f / 6.0f)) * (1.0f / 5.0f);
            minstd = __builtin_amdgcn_sqrtf(fmaxf(var, 0.0f));
        }

        s1 = wave_sum64(s1);
        s2 = wave_sum64(s2);
        c1 = wave_sum64(c1);
        c2 = wave_sum64(c2);
        u1 = wave_sum64(u1);
        u2 = wave_sum64(u2);
        minstd = wave_min64(minstd);

        if (t == 63) {
            float bv = fmaxf((s2 - s1 * s1 * (1.0f / 256.0f)) * (1.0f / 255.0f), 0.0f);
            bool active = bv > ACT_TH;
            float cstd = __builtin_amdgcn_sqrtf(
                fmaxf((c2 - c1 * c1 * (1.0f / 32.0f)) * (1.0f / 31.0f), 0.0f));
            float sstd = __builtin_amdgcn_sqrtf(
                fmaxf((u2 - u1 * u1 * (1.0f / 224.0f)) * (1.0f / 223.0f), 0.0f));
            float csd = cstd / sstd;            // 0/0 -> NaN (matches ref)
            if (csd != csd) csd = 0.0f;
            float sigma = __builtin_amdgcn_sqrtf(bv);
            float beta = fabsf(sigma - csd) / fmaxf(sigma, csd);
            bool wnc = sigma > 2.0f * beta;     // NaN beta -> false (matches)
            bool impaired = minstd < IMP_TH;
            if (active) {
                float contrib = (impaired ? (1.0f - bv) : 0.0f) + (wnc ? bv : 0.0f);
                atomicAdd(&s_c, contrib);
                atomicAdd(&s_a, 1u);
            }
        }
    }
    __syncthreads();
    if (tid == 0) {
        atomicAdd(&contrib_sum[b], s_c);
        atomicAdd(&nhsa[b], s_a);
    }
}

// ---------------- Kernel 3: final score ----------------------------------
__global__ void piqe_finish_kernel(const float* __restrict__ contrib_sum,
                                   const unsigned int* __restrict__ nhsa,
                                   float* __restrict__ out)
{
    int b = threadIdx.x;
    if (b < NBATCH)
        out[b] = (contrib_sum[b] + 1.0f) / (1.0f + (float)nhsa[b]) * 100.0f;
}

extern "C" void kernel_launch(void* const* d_in, const int* in_sizes, int n_in,
                              void* d_out, int out_size, void* d_ws, size_t ws_size,
                              hipStream_t stream)
{
    const float* x = (const float*)d_in[0];
    float* out = (float*)d_out;

    unsigned int* maxbits = (unsigned int*)d_ws;                 // 8 u32 @ 0
    float* contrib = (float*)((char*)d_ws + 32);                 // 8 f32 @ 32
    unsigned int* nhsa = (unsigned int*)((char*)d_ws + 64);      // 8 u32 @ 64

    hipMemsetAsync(d_ws, 0, 96, stream);
    batch_max_kernel<<<dim3(256, NBATCH), 256, 0, stream>>>(x, maxbits);
    piqe_main_kernel<<<dim3(IW / TW, IH / TH, NBATCH), 256, 0, stream>>>(
        x, maxbits, contrib, nhsa);
    piqe_finish_kernel<<<1, 64, 0, stream>>>(contrib, nhsa, out);
}